// Round 8
// baseline (2233.644 us; speedup 1.0000x reference)
//
#include <hip/hip_runtime.h>

#define DIM 512
#define NROWS 131072
#define MB 128                    // rows per block

typedef __attribute__((ext_vector_type(8))) __bf16 bf16x8;
typedef __attribute__((ext_vector_type(4))) float f32x4;

__device__ __forceinline__ unsigned short f2bf(float f) {
  unsigned u = __builtin_bit_cast(unsigned, f);
  return (unsigned short)((u + 0x7FFFu + ((u >> 16) & 1u)) >> 16);
}
__device__ __forceinline__ float bf2f(unsigned short u) {
  return __builtin_bit_cast(float, (unsigned)u << 16);
}

__device__ __forceinline__ f32x4 mfma16(bf16x8 a, bf16x8 b, f32x4 c) {
  return __builtin_amdgcn_mfma_f32_16x16x32_bf16(a, b, c, 0, 0, 0);
}

__device__ __forceinline__ float sigmoid_fast(float v) {
  return 1.0f / (1.0f + __expf(-v));
}
__device__ __forceinline__ float tanh_fast(float v) {
  float e = __expf(2.0f * v);
  return 1.0f - 2.0f / (e + 1.0f);
}

// ---------------------------------------------------------------------------
// Weight pre-pack: fp32 W[out=512][in=512] -> bf16 B-fragments.
// Frag (gate g, kstep f, colfrag c): lane l holds 8 bf16 =
//   W[c*16 + (l&15)][f*32 + (l>>4)*8 + 0..7]
// elem index = ((g*16+f)*32 + c)*512 + l*8 + e.  Gates: rx,zx,rh,zh,nx,nh.
// ---------------------------------------------------------------------------
__global__ void prepack_weights(const float* __restrict__ W0, const float* __restrict__ W1,
                                const float* __restrict__ W2, const float* __restrict__ W3,
                                const float* __restrict__ W4, const float* __restrict__ W5,
                                unsigned short* __restrict__ out) {
  int idx = blockIdx.x * 256 + threadIdx.x;
  int e = idx & 7;
  int l = (idx >> 3) & 63;
  int c = (idx >> 9) & 31;
  int f = (idx >> 14) & 15;
  int g = idx >> 18;
  const float* W = (g == 0) ? W0 : (g == 1) ? W1 : (g == 2) ? W2
                 : (g == 3) ? W3 : (g == 4) ? W4 : W5;
  int row = c * 16 + (l & 15);
  int kk  = f * 32 + ((l >> 4) << 3) + e;
  out[idx] = f2bf(W[row * DIM + kk]);
}

// generic fp32 -> bf16 row-major copy (for x and h)
__global__ void prep_bf16(const float* __restrict__ in, unsigned short* __restrict__ ob) {
  size_t i = (size_t)(blockIdx.x * 256 + threadIdx.x) * 8;
  float4 a0 = *(const float4*)(in + i);
  float4 a1 = *(const float4*)(in + i + 4);
  union { unsigned short us[8]; uint4 v; } p;
  p.us[0] = f2bf(a0.x); p.us[1] = f2bf(a0.y); p.us[2] = f2bf(a0.z); p.us[3] = f2bf(a0.w);
  p.us[4] = f2bf(a1.x); p.us[5] = f2bf(a1.y); p.us[6] = f2bf(a1.z); p.us[7] = f2bf(a1.w);
  *(uint4*)(ob + i) = p.v;
}

// ---------------------------------------------------------------------------
// Fused GRU, Mb=128, three single-accumulator sweeps (Z, R, N).
// Block = 128 rows x 512 cols, 8 waves (2 row-groups x 4 col-groups),
// wave = 64r x 128c, acc[4][8] (128 regs).  All A/B operands are direct
// global->reg loads (bf16); LDS holds only rh frags (128 KB), written at the
// r-epilogue, read (conflict-free) in sweep N.  z staged fp32 in d_out.
// One __syncthreads total.  Weight cache traffic = 1024 blocks x 3 MB = 3 GB.
// ---------------------------------------------------------------------------
__global__ __launch_bounds__(512, 2)
void gru_fused(const float* __restrict__ x, const float* __restrict__ h,
               const unsigned short* __restrict__ xb,
               const unsigned short* __restrict__ hb,    // bf16 h or null
               const unsigned char* __restrict__ WB,
               const float* __restrict__ b_rx, const float* __restrict__ b_rh,
               const float* __restrict__ b_zx, const float* __restrict__ b_zh,
               const float* __restrict__ b_nx, const float* __restrict__ b_nh,
               float* __restrict__ out) {
  __shared__ __align__(1024) unsigned char lds[131072];

  const int tid  = threadIdx.x;
  const int lane = tid & 63;
  const int w    = tid >> 6;
  const int wr   = w >> 2;           // row group 0..1
  const int wc   = w & 3;            // col group 0..3
  const int row0 = blockIdx.x * MB;
  const int rb   = row0 + wr * 64;   // wave's first row
  const int lr   = lane & 15;
  const int lk   = lane >> 4;

  bf16x8 bX[8], bH[8], axA[4], axB[4], ahC[4];
  f32x4 acc[4][8];

  auto loadB = [&](int g, int f, bf16x8 (&b)[8]) {
    const unsigned char* p = WB + (((size_t)(g * 16 + f)) << 15)
                             + (wc * 8) * 1024 + lane * 16;
#pragma unroll
    for (int cf = 0; cf < 8; ++cf)
      b[cf] = *(const bf16x8*)(p + cf * 1024);
  };
  auto loadA = [&](const unsigned short* bp, const float* fp, int f, bf16x8 (&a)[4]) {
    if (bp) {
#pragma unroll
      for (int rf = 0; rf < 4; ++rf)
        a[rf] = *(const bf16x8*)(bp + (size_t)(rb + rf * 16 + lr) * DIM
                                 + f * 32 + lk * 8);
    } else {
#pragma unroll
      for (int rf = 0; rf < 4; ++rf) {
        const float* p = fp + (size_t)(rb + rf * 16 + lr) * DIM + f * 32 + lk * 8;
        float4 u0 = *(const float4*)p;
        float4 u1 = *(const float4*)(p + 4);
        union { unsigned short us[8]; bf16x8 v; } c;
        c.us[0]=f2bf(u0.x); c.us[1]=f2bf(u0.y); c.us[2]=f2bf(u0.z); c.us[3]=f2bf(u0.w);
        c.us[4]=f2bf(u1.x); c.us[5]=f2bf(u1.y); c.us[6]=f2bf(u1.z); c.us[7]=f2bf(u1.w);
        a[rf] = c.v;
      }
    }
  };
  auto readRH = [&](int f, bf16x8 (&a)[4]) {
#pragma unroll
    for (int rf = 0; rf < 4; ++rf)
      a[rf] = *(const bf16x8*)&lds[f * 8192 + (wr * 4 + rf) * 1024 + lane * 16];
  };

#define WIN(A, B)                                                              \
  do {                                                                         \
    __builtin_amdgcn_s_setprio(1);                                             \
    _Pragma("unroll")                                                          \
    for (int rf_ = 0; rf_ < 4; ++rf_)                                          \
      _Pragma("unroll")                                                        \
      for (int cf_ = 0; cf_ < 8; ++cf_)                                        \
        acc[rf_][cf_] = mfma16(A[rf_], B[cf_], acc[rf_][cf_]);                 \
    __builtin_amdgcn_s_setprio(0);                                             \
  } while (0)

#define LOADAH_G(F)  loadA(hb, h, (F), ahC)
#define LOADAH_RH(F) readRH((F), ahC)

  // per f: window1 = gate GX with A=x, window2 = gate GH with A=ahC.
  // x ping-pongs axA/axB (no copies); B and ah reload in place after use.
#define SWEEP(GX, GH, AH)                                                      \
  {                                                                            \
    _Pragma("unroll")                                                          \
    for (int rf_ = 0; rf_ < 4; ++rf_)                                          \
      _Pragma("unroll")                                                        \
      for (int cf_ = 0; cf_ < 8; ++cf_)                                        \
        acc[rf_][cf_] = (f32x4){0.f, 0.f, 0.f, 0.f};                           \
    loadB((GX), 0, bX); loadB((GH), 0, bH);                                    \
    loadA(xb, x, 0, axA); AH(0);                                               \
    _Pragma("unroll 1")                                                        \
    for (int f2 = 0; f2 < 8; ++f2) {                                           \
      {                                                                        \
        const int f1 = 2 * f2 + 1;                                             \
        loadA(xb, x, f1, axB);                                                 \
        WIN(axA, bX); loadB((GX), f1, bX);                                     \
        WIN(ahC, bH); loadB((GH), f1, bH); AH(f1);                             \
      }                                                                        \
      {                                                                        \
        const int f1 = (f2 < 7) ? 2 * f2 + 2 : 15;                             \
        loadA(xb, x, f1, axA);                                                 \
        WIN(axB, bX); loadB((GX), f1, bX);                                     \
        WIN(ahC, bH); loadB((GH), f1, bH); AH(f1);                             \
      }                                                                        \
    }                                                                          \
  }

  // ================= sweep Z: z = sigmoid(x@Wzx + h@Wzh + b) ================
  SWEEP(1, 3, LOADAH_G);
#pragma unroll
  for (int cf = 0; cf < 8; ++cf) {
    const int col = wc * 128 + cf * 16 + lr;
    const float bz = b_zx[col] + b_zh[col];
#pragma unroll
    for (int rf = 0; rf < 4; ++rf)
#pragma unroll
      for (int j = 0; j < 4; ++j) {
        const int row = rb + rf * 16 + lk * 4 + j;
        out[(size_t)row * DIM + col] = sigmoid_fast(acc[rf][cf][j] + bz);
      }
  }

  // ============ sweep R: r = sigmoid(...); rh = r*h -> LDS frags ============
  SWEEP(0, 2, LOADAH_G);
#pragma unroll
  for (int cf = 0; cf < 8; ++cf) {
    const int col = wc * 128 + cf * 16 + lr;
    const float bs = b_rx[col] + b_rh[col];
    const int fI  = col >> 5;
    const int l2b = ((col >> 3) & 3) * 16;
    const int eb  = (col & 7) * 2;
#pragma unroll
    for (int rf = 0; rf < 4; ++rf) {
#pragma unroll
      for (int j = 0; j < 4; ++j) {
        const int rsub = lk * 4 + j;
        const int row  = rb + rf * 16 + rsub;
        const size_t off = (size_t)row * DIM + col;
        float hv = hb ? bf2f(hb[off]) : h[off];
        float rv = sigmoid_fast(acc[rf][cf][j] + bs);
        *(unsigned short*)&lds[fI * 8192 + (wr * 4 + rf) * 1024
                               + (l2b + rsub) * 16 + eb] = f2bf(rv * hv);
      }
    }
  }
  __syncthreads();                     // rh frags visible to all waves

  // ======== sweep N: n = tanh(x@Wnx + rh@Wnh + b); combine epilogue ========
  SWEEP(4, 5, LOADAH_RH);
#pragma unroll
  for (int cf = 0; cf < 8; ++cf) {
    const int col = wc * 128 + cf * 16 + lr;
    const float bn = b_nx[col] + b_nh[col];
#pragma unroll
    for (int rf = 0; rf < 4; ++rf) {
#pragma unroll
      for (int j = 0; j < 4; ++j) {
        const int row = rb + rf * 16 + lk * 4 + j;
        const size_t off = (size_t)row * DIM + col;
        float nv = tanh_fast(acc[rf][cf][j] + bn);
        float zv = out[off];           // z staged here by sweep Z
        float hv = h[off];
        out[off] = (1.0f - zv) * nv + zv * hv;
      }
    }
  }
#undef SWEEP
#undef WIN
#undef LOADAH_G
#undef LOADAH_RH
}

extern "C" void kernel_launch(void* const* d_in, const int* in_sizes, int n_in,
                              void* d_out, int out_size, void* d_ws, size_t ws_size,
                              hipStream_t stream) {
  const float* x    = (const float*)d_in[0];
  const float* h    = (const float*)d_in[1];
  const float* W_rx = (const float*)d_in[2];
  const float* b_rx = (const float*)d_in[3];
  const float* W_rh = (const float*)d_in[4];
  const float* b_rh = (const float*)d_in[5];
  const float* W_zx = (const float*)d_in[6];
  const float* b_zx = (const float*)d_in[7];
  const float* W_zh = (const float*)d_in[8];
  const float* b_zh = (const float*)d_in[9];
  const float* W_nx = (const float*)d_in[10];
  const float* b_nx = (const float*)d_in[11];
  const float* W_nh = (const float*)d_in[12];
  const float* b_nh = (const float*)d_in[13];

  unsigned char* ws = (unsigned char*)d_ws;
  unsigned short* wpack = (unsigned short*)ws;                  // 3 MiB @ 0
  const size_t xb_off = 4ull << 20;
  const size_t hb_off = xb_off + (size_t)NROWS * DIM * 2;       // +128 MiB
  const size_t need_x = hb_off;                                 // 132 MiB
  const size_t need_h = hb_off + (size_t)NROWS * DIM * 2;       // 260 MiB
  unsigned short* xb = (ws_size >= need_x) ? (unsigned short*)(ws + xb_off)
                                           : (unsigned short*)nullptr;
  unsigned short* hb = (ws_size >= need_h) ? (unsigned short*)(ws + hb_off)
                                           : (unsigned short*)nullptr;

  // gate order: rx, zx, rh, zh, nx, nh
  prepack_weights<<<6144, 256, 0, stream>>>(W_rx, W_zx, W_rh, W_zh, W_nx, W_nh, wpack);
  if (xb) prep_bf16<<<32768, 256, 0, stream>>>(x, xb);
  if (hb) prep_bf16<<<32768, 256, 0, stream>>>(h, hb);
  gru_fused<<<NROWS / MB, 512, 0, stream>>>(x, h, xb, hb,
                                            (const unsigned char*)wpack,
                                            b_rx, b_rh, b_zx, b_zh, b_nx, b_nh,
                                            (float*)d_out);
}

// Round 9
// 837.260 us; speedup vs baseline: 2.6678x; 2.6678x over previous
//
#include <hip/hip_runtime.h>

#define DIM 512
#define NROWS 131072

typedef __attribute__((ext_vector_type(8))) __bf16 bf16x8;
typedef __attribute__((ext_vector_type(4))) float f32x4;

__device__ __forceinline__ unsigned short f2bf(float f) {
  unsigned u = __builtin_bit_cast(unsigned, f);
  return (unsigned short)((u + 0x7FFFu + ((u >> 16) & 1u)) >> 16);
}
__device__ __forceinline__ float bf2f(unsigned short u) {
  return __builtin_bit_cast(float, (unsigned)u << 16);
}
__device__ __forceinline__ f32x4 mfma16(bf16x8 a, bf16x8 b, f32x4 c) {
  return __builtin_amdgcn_mfma_f32_16x16x32_bf16(a, b, c, 0, 0, 0);
}
__device__ __forceinline__ float sigmoid_fast(float v) {
  return 1.0f / (1.0f + __expf(-v));
}
__device__ __forceinline__ float tanh_fast(float v) {
  float e = __expf(2.0f * v);
  return 1.0f - 2.0f / (e + 1.0f);
}
__device__ __forceinline__ void gl2lds(const void* g, void* l) {
  __builtin_amdgcn_global_load_lds(
      (const __attribute__((address_space(1))) unsigned int*)g,
      (__attribute__((address_space(3))) unsigned int*)l, 16, 0, 0);
}

// ---------------------------------------------------------------------------
// Weight pre-pack: fp32 W[out=512][in=512] -> bf16 B-fragments.
// Frag (gate g, kstep f, colfrag c): lane l holds 8 bf16 =
//   W[c*16 + (l&15)][f*32 + (l>>4)*8 + 0..7]
// elem index = ((g*16+f)*32 + c)*512 + l*8 + e.  Gates: rx,zx,rh,zh,nx,nh.
// ---------------------------------------------------------------------------
__global__ void prepack_weights(const float* __restrict__ W0, const float* __restrict__ W1,
                                const float* __restrict__ W2, const float* __restrict__ W3,
                                const float* __restrict__ W4, const float* __restrict__ W5,
                                unsigned short* __restrict__ out) {
  int idx = blockIdx.x * 256 + threadIdx.x;
  int e = idx & 7;
  int l = (idx >> 3) & 63;
  int c = (idx >> 9) & 31;
  int f = (idx >> 14) & 15;
  int g = idx >> 18;
  const float* W = (g == 0) ? W0 : (g == 1) ? W1 : (g == 2) ? W2
                 : (g == 3) ? W3 : (g == 4) ? W4 : W5;
  int row = c * 16 + (l & 15);
  int kk  = f * 32 + ((l >> 4) << 3) + e;
  out[idx] = f2bf(W[row * DIM + kk]);
}

// x -> bf16 row-major (direct per-lane A-fragment register loads)
__global__ void prep_x(const float* __restrict__ x, unsigned short* __restrict__ xb) {
  size_t i = (size_t)(blockIdx.x * 256 + threadIdx.x) * 8;
  float4 a0 = *(const float4*)(x + i);
  float4 a1 = *(const float4*)(x + i + 4);
  union { unsigned short us[8]; uint4 v; } p;
  p.us[0] = f2bf(a0.x); p.us[1] = f2bf(a0.y); p.us[2] = f2bf(a0.z); p.us[3] = f2bf(a0.w);
  p.us[4] = f2bf(a1.x); p.us[5] = f2bf(a1.y); p.us[6] = f2bf(a1.z); p.us[7] = f2bf(a1.w);
  *(uint4*)(xb + i) = p.v;
}

// LDS map: [0,64K) h frags (rh after r-epilogue); [64K,160K) B triple-buffer.
#define BOFF 65536
#define LDS_BYTES 163840

// ---------------------------------------------------------------------------
// Fused GRU, lead-2 counted-vmcnt pipeline, triple-buffered B staging.
// Block = 64r x 512c, 8 waves col-split, wave = 64r x 64c, 16 MFMA/window.
// Window = {vmcnt(N); s_barrier; issue next stages (gl2lds/reg); ds_read;
// MFMA}.  Stage issued at window w is consumed at w+2 (buf (w+2)%3); a
// buffer's overwrite begins 2 barrier-synced windows after its last read.
// x-fragments are direct global->reg loads from xb (compiler-counted).
// ---------------------------------------------------------------------------
__global__ __launch_bounds__(512, 1)
void gru_fused(const float* __restrict__ h,
               const unsigned short* __restrict__ xb,
               const unsigned char* __restrict__ WB,
               const float* __restrict__ b_rx, const float* __restrict__ b_rh,
               const float* __restrict__ b_zx, const float* __restrict__ b_zh,
               const float* __restrict__ b_nx, const float* __restrict__ b_nh,
               float* __restrict__ out) {
  __shared__ __align__(1024) unsigned char lds[LDS_BYTES];

  const int tid  = threadIdx.x;
  const int lane = tid & 63;
  const int w    = tid >> 6;
  const int cfg0 = w * 4;
  const int row0 = blockIdx.x * 64;
  const int lr   = lane & 15;
  const int lk   = lane >> 4;

  auto stageB = [&](int g, int f, int buf) {   // 32KB chunk, 4 gl2lds/thread
    const unsigned char* src = WB + (size_t)(g * 16 + f) * 32768;
#pragma unroll
    for (int it = 0; it < 4; ++it) {
      int o = (it * 512 + tid) * 16;
      gl2lds(src + o, &lds[BOFF + buf * 32768 + o]);
    }
  };
  auto loadXA = [&](int f, bf16x8 (&a)[4]) {   // x frags global->reg
#pragma unroll
    for (int rf = 0; rf < 4; ++rf)
      a[rf] = *(const bf16x8*)(xb + (size_t)(row0 + rf * 16 + lr) * DIM
                               + f * 32 + lk * 8);
  };
  auto readAh = [&](int f, bf16x8 (&a)[4]) {   // h/rh frags from LDS
#pragma unroll
    for (int rf = 0; rf < 4; ++rf)
      a[rf] = *(const bf16x8*)&lds[f * 4096 + rf * 1024 + lane * 16];
  };
  auto readB = [&](int buf, bf16x8 (&b)[4]) {
#pragma unroll
    for (int cf = 0; cf < 4; ++cf)
      b[cf] = *(const bf16x8*)&lds[BOFF + buf * 32768 + (cfg0 + cf) * 1024
                                   + lane * 16];
  };

#define WIN(A, B, ACC)                                                         \
  do {                                                                         \
    __builtin_amdgcn_s_setprio(1);                                             \
    _Pragma("unroll")                                                          \
    for (int rf_ = 0; rf_ < 4; ++rf_)                                          \
      _Pragma("unroll")                                                        \
      for (int cf_ = 0; cf_ < 4; ++cf_)                                        \
        ACC[rf_][cf_] = mfma16(A[rf_], B[cf_], ACC[rf_][cf_]);                 \
    __builtin_amdgcn_s_setprio(0);                                             \
  } while (0)

  bf16x8 afx[4], afxN[4], afh[4], bfr[4];

  // ---- prologue: x(0) regs; stage rx0->buf0, zx0->buf1; h -> frag LDS ----
  loadXA(0, afx);
  stageB(0, 0, 0);
  stageB(1, 0, 1);
#pragma unroll
  for (int it = 0; it < 16; ++it) {
    int i = tid + it * 512;
    int row = i >> 7;
    int k = (i & 127) * 4;
    float4 hv4 = *(const float4*)(h + (size_t)(row0 + row) * DIM + k);
    union { unsigned short us[4]; uint2 v; } p;
    p.us[0] = f2bf(hv4.x); p.us[1] = f2bf(hv4.y);
    p.us[2] = f2bf(hv4.z); p.us[3] = f2bf(hv4.w);
    *(uint2*)&lds[(k >> 5) * 4096 + (row >> 4) * 1024
                  + (((k >> 3) & 3) * 16 + (row & 15)) * 16 + (k & 4) * 2] = p.v;
  }
  __syncthreads();                       // full drain; pipeline starts clean

  // ---- sweep 1: f x {W0=rx, W1=zx, W2=rh, W3=zh} ----
  f32x4 accR[4][4] = {}, accZ[4][4] = {};
  int c0 = 0;                            // window 4f consumes buf (f%3)
#pragma unroll 1
  for (int f = 0; f < 16; ++f) {
    const int c1 = (c0 == 2) ? 0 : c0 + 1;
    const int c2 = (c1 == 2) ? 0 : c1 + 1;
    // W0: rx(f) @ c0; issue rh(f)->c2
    asm volatile("s_waitcnt vmcnt(4)" ::: "memory");
    __builtin_amdgcn_s_barrier();
    stageB(2, f, c2);
    readB(c0, bfr);
    WIN(afx, bfr, accR);
    // W1: zx(f) @ c1; issue zh(f)->c0
    asm volatile("s_waitcnt vmcnt(4)" ::: "memory");
    __builtin_amdgcn_s_barrier();
    stageB(3, f, c0);
    readB(c1, bfr);
    WIN(afx, bfr, accZ);
    // W2: rh(f) @ c2; issue x(f+1) + rx(f+1)->c1   (f=15: x(0) + nx0->c1)
    asm volatile("s_waitcnt vmcnt(4)" ::: "memory");
    __builtin_amdgcn_s_barrier();
    if (f < 15) { loadXA(f + 1, afxN); stageB(0, f + 1, c1); }
    else        { loadXA(0, afxN);     stageB(4, 0, c1); }
    readAh(f, afh);
    readB(c2, bfr);
    WIN(afh, bfr, accR);
    // W3: zh(f) @ c0; issue zx(f+1)->c2            (f=15: nh0->c2)
    asm volatile("s_waitcnt vmcnt(8)" ::: "memory");
    __builtin_amdgcn_s_barrier();
    stageB((f < 15) ? 1 : 5, (f < 15) ? f + 1 : 0, c2);
    readB(c0, bfr);
    WIN(afh, bfr, accZ);
#pragma unroll
    for (int i2 = 0; i2 < 4; ++i2) afx[i2] = afxN[i2];
    c0 = c1;
  }

  // ---- r-epilogue: rh = sigmoid(accR+b)*h, in place in the h-frag LDS ----
  __builtin_amdgcn_s_barrier();          // all waves done reading h frags
#pragma unroll
  for (int cf = 0; cf < 4; ++cf) {
    const int col  = (cfg0 + cf) * 16 + lr;
    const float bs = b_rx[col] + b_rh[col];
    const int fI  = col >> 5;
    const int l2b = ((col >> 3) & 3) * 16;
    const int eb  = (col & 7) * 2;
#pragma unroll
    for (int rf = 0; rf < 4; ++rf) {
#pragma unroll
      for (int j = 0; j < 4; ++j) {
        const int rsub = lk * 4 + j;
        const int addr = fI * 4096 + rf * 1024 + (l2b + rsub) * 16 + eb;
        unsigned short hu = *(const unsigned short*)&lds[addr];
        float rv = sigmoid_fast(accR[rf][cf][j] + bs);
        *(unsigned short*)&lds[addr] = f2bf(rv * bf2f(hu));
      }
    }
  }
  asm volatile("s_waitcnt lgkmcnt(0)" ::: "memory");   // rh writes landed

  // ---- sweep 2: f x {V0=nx, V1=nh(A=rh frags)} ----
  f32x4 accN[4][4] = {};
  int d0 = 1;                            // window 64+2f consumes buf (1+2f)%3
#pragma unroll 1
  for (int f = 0; f < 15; ++f) {
    const int d1 = (d0 == 2) ? 0 : d0 + 1;
    const int e0 = (d1 == 2) ? 0 : d1 + 1;
    const int e1 = (e0 == 2) ? 0 : e0 + 1;
    // V0: nx(f) @ d0; issue x(f+1) + nx(f+1)->e0
    asm volatile("s_waitcnt vmcnt(4)" ::: "memory");
    __builtin_amdgcn_s_barrier();
    loadXA(f + 1, afxN);
    stageB(4, f + 1, e0);
    readB(d0, bfr);
    WIN(afx, bfr, accN);
    // V1: nh(f) @ d1; issue nh(f+1)->e1
    asm volatile("s_waitcnt vmcnt(8)" ::: "memory");
    __builtin_amdgcn_s_barrier();
    stageB(5, f + 1, e1);
    readAh(f, afh);
    readB(d1, bfr);
    WIN(afh, bfr, accN);
#pragma unroll
    for (int i2 = 0; i2 < 4; ++i2) afx[i2] = afxN[i2];
    d0 = e0;
  }
  {  // f = 15, peeled (no further stages; drain)
    asm volatile("s_waitcnt vmcnt(4)" ::: "memory");
    __builtin_amdgcn_s_barrier();
    readB(d0, bfr);
    WIN(afx, bfr, accN);
    const int d1 = (d0 == 2) ? 0 : d0 + 1;
    asm volatile("s_waitcnt vmcnt(0)" ::: "memory");
    __builtin_amdgcn_s_barrier();
    readAh(15, afh);
    readB(d1, bfr);
    WIN(afh, bfr, accN);
  }

  // ---- final epilogue: n = tanh(accN+b), z = sigmoid(accZ+b), combine ----
#pragma unroll
  for (int cf = 0; cf < 4; ++cf) {
    const int col  = (cfg0 + cf) * 16 + lr;
    const float bn = b_nx[col] + b_nh[col];
    const float bz = b_zx[col] + b_zh[col];
#pragma unroll
    for (int rf = 0; rf < 4; ++rf) {
#pragma unroll
      for (int j = 0; j < 4; ++j) {
        const int row = rf * 16 + lk * 4 + j;
        const size_t off = (size_t)(row0 + row) * DIM + col;
        float hv = h[off];
        float nv = tanh_fast(accN[rf][cf][j] + bn);
        float zv = sigmoid_fast(accZ[rf][cf][j] + bz);
        out[off] = (1.0f - zv) * nv + zv * hv;
      }
    }
  }
#undef WIN
}

extern "C" void kernel_launch(void* const* d_in, const int* in_sizes, int n_in,
                              void* d_out, int out_size, void* d_ws, size_t ws_size,
                              hipStream_t stream) {
  const float* x    = (const float*)d_in[0];
  const float* h    = (const float*)d_in[1];
  const float* W_rx = (const float*)d_in[2];
  const float* b_rx = (const float*)d_in[3];
  const float* W_rh = (const float*)d_in[4];
  const float* b_rh = (const float*)d_in[5];
  const float* W_zx = (const float*)d_in[6];
  const float* b_zx = (const float*)d_in[7];
  const float* W_zh = (const float*)d_in[8];
  const float* b_zh = (const float*)d_in[9];
  const float* W_nx = (const float*)d_in[10];
  const float* b_nx = (const float*)d_in[11];
  const float* W_nh = (const float*)d_in[12];
  const float* b_nh = (const float*)d_in[13];

  unsigned char* ws = (unsigned char*)d_ws;
  unsigned short* wpack = (unsigned short*)ws;                  // 3 MiB
  unsigned short* xb    = (unsigned short*)(ws + (4ull << 20)); // 128 MiB (proven fits)

  // gate order: rx, zx, rh, zh, nx, nh
  prepack_weights<<<6144, 256, 0, stream>>>(W_rx, W_zx, W_rh, W_zh, W_nx, W_nh, wpack);
  prep_x<<<32768, 256, 0, stream>>>(x, xb);
  gru_fused<<<NROWS / 64, 512, 0, stream>>>(h, xb, (const unsigned char*)wpack,
                                            b_rx, b_rh, b_zx, b_zh, b_nx, b_nh,
                                            (float*)d_out);
}